// Round 1
// baseline (637.597 us; speedup 1.0000x reference)
//
#include <hip/hip_runtime.h>

#define TB 512

// Problem constants: B=32, R=2, T=128, N=128, C_IN=64, C_OUT=64
constexpr size_t XOUT_ELEMS = 32ull * 64 * 128 * 128;  // 33,554,432

__global__ __launch_bounds__(TB, 1)
void gcn_fused(const float* __restrict__ xg, const float* __restrict__ Ag,
               const float* __restrict__ Wg, const float* __restrict__ bg,
               float* __restrict__ outg)
{
    // LDS layout (floats):
    //   yt  [128][132] @ 0       : y transposed, yt[n][o]; padded row stride 132
    //   region B @ 16896 (16384 floats):
    //       phase1/2: shx[64][128] + shw(=W^T)[64][128]
    //       phase3:   shA[128][128]
    //   rs[128] @ 33280, dd[128] @ 33408   (total 33536 floats = 134,144 B)
    __shared__ float smem[33536];
    float* yt  = smem;
    float* shx = smem + 16896;
    float* shw = smem + 16896 + 8192;
    float* shA = smem + 16896;
    float* rs  = smem + 33280;
    float* dd  = smem + 33408;

    const int tid = threadIdx.x;
    const int blk = blockIdx.x;
    const int b = blk >> 7;    // blk / 128
    const int t = blk & 127;   // blk % 128

    float4* yt4  = (float4*)yt;
    float4* shx4 = (float4*)shx;
    float4* shA4 = (float4*)shA;
    const float4* x4 = (const float4*)xg;

    // ---------------- phase 1: stage x tile and W^T ----------------
    // x[b, c, t, :] for c in [0,64): 2048 float4, coalesced
    #pragma unroll
    for (int k = 0; k < 4; ++k) {
        int q = tid + TB * k;          // < 2048
        int c = q >> 5, nf = q & 31;   // 32 float4 per row
        shx4[c * 32 + nf] = x4[((size_t)(b * 64 + c) * 128 + t) * 32 + nf];
    }
    // W is (128 o, 64 c) row-major; store transposed shw[c][o] so phase 2
    // reads contiguous o-fragments. LDS writes conflict-free (consecutive o).
    #pragma unroll
    for (int k = 0; k < 16; ++k) {
        int p = tid + TB * k;          // < 8192
        int o = p & 127, c = p >> 7;
        shw[c * 128 + o] = Wg[o * 64 + c];
    }
    __syncthreads();

    // ---------------- phase 2: y[o][n] = sum_c W[o][c]*x[c][n] + b[o] ----------------
    // thread tile: 8 o x 4 n.  oi = tid>>5 (16 groups * 8 = 128 o), ni = tid&31 (*4 = 128 n)
    {
        const int oi = tid >> 5, ni = tid & 31;
        const int o0 = oi * 8;
        float yr[8][4];
        #pragma unroll
        for (int i = 0; i < 8; ++i) {
            float bb = bg[o0 + i];
            yr[i][0] = bb; yr[i][1] = bb; yr[i][2] = bb; yr[i][3] = bb;
        }
        const float4* shw4 = (const float4*)shw;
        #pragma unroll 4
        for (int c = 0; c < 64; ++c) {
            float4 w0 = shw4[c * 32 + (o0 >> 2)];
            float4 w1 = shw4[c * 32 + (o0 >> 2) + 1];
            float4 xv = shx4[c * 32 + ni];
            float wa[8] = {w0.x, w0.y, w0.z, w0.w, w1.x, w1.y, w1.z, w1.w};
            #pragma unroll
            for (int i = 0; i < 8; ++i) {
                yr[i][0] += wa[i] * xv.x;
                yr[i][1] += wa[i] * xv.y;
                yr[i][2] += wa[i] * xv.z;
                yr[i][3] += wa[i] * xv.w;
            }
        }
        // store transposed: yt[n][o] = y[o][n]
        const int n0 = ni * 4;
        #pragma unroll
        for (int j = 0; j < 4; ++j) {
            float4 a0 = make_float4(yr[0][j], yr[1][j], yr[2][j], yr[3][j]);
            float4 a1 = make_float4(yr[4][j], yr[5][j], yr[6][j], yr[7][j]);
            int base = (n0 + j) * 33 + (o0 >> 2);   // 132/4 = 33
            yt4[base]     = a0;
            yt4[base + 1] = a1;
        }
    }
    __syncthreads();

    // ---------------- phase 3: per relation r ----------------
    const int ci = tid >> 5, ni = tid & 31;   // GEMM tile: 4 c x 4 n per thread
    const int c0 = ci * 4;
    float tot[4][4] = {};

    for (int r = 0; r < 2; ++r) {
        const size_t aoff = (((size_t)b * 2 + r) * 128 + t) * 16384;
        const float4* gA4 = (const float4*)(Ag + aoff);
        float4*       gO4 = (float4*)(outg + XOUT_ELEMS + aoff);  // fused A-copy

        // 3a: stage A tile to LDS + copy to out + rowsums in-register.
        // p = tid + 512k -> row = (tid>>5) + 16k; the 32 lanes (tid&31) of a
        // half-wave hold exactly that row's 32 float4 chunks -> shfl reduce.
        #pragma unroll
        for (int k = 0; k < 8; ++k) {
            int p = tid + TB * k;   // < 4096 float4
            float4 v = gA4[p];
            shA4[p] = v;
            gO4[p]  = v;
            float s = v.x + v.y + v.z + v.w;
            s += __shfl_xor(s, 16, 32);
            s += __shfl_xor(s,  8, 32);
            s += __shfl_xor(s,  4, 32);
            s += __shfl_xor(s,  2, 32);
            s += __shfl_xor(s,  1, 32);
            if ((tid & 31) == 0) rs[(tid >> 5) + 16 * k] = s;
        }
        __syncthreads();

        // 3b: d[m] = rsqrt(1 + rowsum); fold +I into staged diagonal
        if (tid < 128) {
            float dv = rsqrtf(1.0f + rs[tid]);
            dd[tid] = dv;
            shA[tid * 128 + tid] += 1.0f;
        }
        __syncthreads();

        // 3c: scale yt rows (spatial m) by d[m], only columns [r*64, r*64+64)
        #pragma unroll
        for (int k = 0; k < 4; ++k) {
            int q = tid + TB * k;       // < 2048 float4
            int m = q >> 4, cf = q & 15;
            float dm = dd[m];
            int idx = m * 33 + r * 16 + cf;
            float4 v = yt4[idx];
            v.x *= dm; v.y *= dm; v.z *= dm; v.w *= dm;
            yt4[idx] = v;
        }
        __syncthreads();

        // 3d: out[c][n] = d[n] * sum_m yd[c][m] * (A+I)[m][n]
        float acc[4][4] = {};
        const int yb = r * 16 + ci;   // float4 column index into yt row
        #pragma unroll 8
        for (int mm = 0; mm < 128; ++mm) {
            float4 yv = yt4[mm * 33 + yb];
            float4 av = shA4[mm * 32 + ni];
            float ya[4] = {yv.x, yv.y, yv.z, yv.w};
            #pragma unroll
            for (int i = 0; i < 4; ++i) {
                acc[i][0] += ya[i] * av.x;
                acc[i][1] += ya[i] * av.y;
                acc[i][2] += ya[i] * av.z;
                acc[i][3] += ya[i] * av.w;
            }
        }
        float4 dn = ((const float4*)dd)[ni];
        #pragma unroll
        for (int i = 0; i < 4; ++i) {
            tot[i][0] += acc[i][0] * dn.x;
            tot[i][1] += acc[i][1] * dn.y;
            tot[i][2] += acc[i][2] * dn.z;
            tot[i][3] += acc[i][3] * dn.w;
        }
        __syncthreads();   // before next r overwrites shA/rs
    }

    // final write: x_out[b, c, t, :]
    #pragma unroll
    for (int i = 0; i < 4; ++i) {
        int c = c0 + i;
        ((float4*)outg)[((size_t)(b * 64 + c) * 128 + t) * 32 + ni] =
            make_float4(tot[i][0], tot[i][1], tot[i][2], tot[i][3]);
    }
}

extern "C" void kernel_launch(void* const* d_in, const int* in_sizes, int n_in,
                              void* d_out, int out_size, void* d_ws, size_t ws_size,
                              hipStream_t stream) {
    const float* x    = (const float*)d_in[0];
    const float* A    = (const float*)d_in[1];
    const float* W    = (const float*)d_in[2];
    const float* bias = (const float*)d_in[3];
    float* out = (float*)d_out;

    dim3 grid(32 * 128);   // one block per (b, t)
    dim3 block(TB);
    hipLaunchKernelGGL(gcn_fused, grid, block, 0, stream, x, A, W, bias, out);
}

// Round 2
// 254.748 us; speedup vs baseline: 2.5029x; 2.5029x over previous
//
#include <hip/hip_runtime.h>
#include <hip/hip_bf16.h>

#define TB 512

// B=32, R=2, T=128, N=128, C_IN=64, C_OUT=64
constexpr size_t XOUT_ELEMS = 32ull * 64 * 128 * 128;  // 33,554,432

typedef short bf16x8  __attribute__((ext_vector_type(8)));
typedef short short4v __attribute__((ext_vector_type(4)));
typedef float f32x4   __attribute__((ext_vector_type(4)));

static __device__ __forceinline__ short f2bf(float f) {
    __hip_bfloat16 hb = __float2bfloat16(f);           // RNE
    return *reinterpret_cast<short*>(&hb);
}
static __device__ __forceinline__ float bf2f(short u) {
    return __uint_as_float(((unsigned)(unsigned short)u) << 16);
}

// LDS byte map (81920 B total = exactly 2 blocks/CU of the 160 KiB pool):
//  [0,16384)      shXT: x^T bf16, row n stride 128B; elem (n,c): n*128 + po*16 + (c&7)*2,
//                 po = (c>>3) ^ ((n>>2)&7).     (dead after GEMM1; [0,512) reused as rs[128] f32)
//  [16384,49152)  yt: y[o][m] bf16, row o stride 256B; elem: 16384 + o*256 + po*16 + (m&7)*2,
//                 po = (m>>3) ^ (o&7)
//  [49152,81920)  shAT: A~^T bf16 (shAT[n][m] = A[m][n]), row n stride 256B;
//                 elem: 49152 + n*256 + po*16 + (m&7)*2, po = (m>>3) ^ ((n>>2)&7)

__global__ __launch_bounds__(TB, 4)
void gcn_fused(const float* __restrict__ xg, const float* __restrict__ Ag,
               const float* __restrict__ Wg, const float* __restrict__ bg,
               float* __restrict__ outg)
{
    __shared__ float4 smem4[5120];
    char*  smem = (char*)smem4;
    float* rs   = (float*)smem;

    const int tid = threadIdx.x;
    const int w   = tid >> 6;     // wave 0..7
    const int l   = tid & 63;
    const int g   = l >> 5;       // half-wave
    const int h   = l & 31;
    const int l15 = l & 15;
    const int l4  = l >> 4;       // 0..3

    const int blk = blockIdx.x;
    const int b = blk >> 7, t = blk & 127;

    // ---------------- P0: stage x^T (bf16, swizzled) ----------------
    // wave w owns c in [8w, 8w+8); c = 8w + 4g + i; thread covers col-quad 4h..4h+3
    {
        float vv[4][4];
        #pragma unroll
        for (int i = 0; i < 4; ++i) {
            int c = 8*w + 4*g + i;
            float4 v = *(const float4*)(xg + ((size_t)(b*64 + c)*128 + t)*128 + 4*h);
            vv[i][0] = v.x; vv[i][1] = v.y; vv[i][2] = v.z; vv[i][3] = v.w;
        }
        int po = w ^ (h & 7);                       // oct = (8w+4g)>>3 = w ; key (n>>2)&7 = h&7
        #pragma unroll
        for (int e = 0; e < 4; ++e) {
            int n = 4*h + e;
            short4v pk;
            pk[0] = f2bf(vv[0][e]); pk[1] = f2bf(vv[1][e]);
            pk[2] = f2bf(vv[2][e]); pk[3] = f2bf(vv[3][e]);
            *(short4v*)(smem + n*128 + po*16 + 8*g) = pk;
        }
    }
    __syncthreads();

    // ---------------- P1: GEMM1  y[o][n] = W[o][:]·x[:][n] + b[o]  (MFMA) ----------------
    // wave w -> o-tile w (o0 = 16w); loop n-tiles. a-frag from global W (fp32->bf16), b-frag from shXT.
    {
        bf16x8 af0, af1;
        float  bia[4];
        const int o = 16*w + l15;
        const float* wp0 = Wg + o*64 + 8*l4;        // k-oct l4 of kstep 0
        const float* wp1 = wp0 + 32;                // kstep 1
        #pragma unroll
        for (int e = 0; e < 8; ++e) { af0[e] = f2bf(wp0[e]); af1[e] = f2bf(wp1[e]); }
        #pragma unroll
        for (int j = 0; j < 4; ++j) bia[j] = bg[16*w + 4*l4 + j];

        #pragma unroll
        for (int nt = 0; nt < 8; ++nt) {
            f32x4 acc = {0.f, 0.f, 0.f, 0.f};
            int n   = 16*nt + l15;
            int key = (n >> 2) & 7;
            {
                int po = (0*4 + l4) ^ key;
                bf16x8 bf = *(const bf16x8*)(smem + n*128 + po*16);
                acc = __builtin_amdgcn_mfma_f32_16x16x32_bf16(af0, bf, acc, 0, 0, 0);
            }
            {
                int po = (1*4 + l4) ^ key;
                bf16x8 bf = *(const bf16x8*)(smem + n*128 + po*16);
                acc = __builtin_amdgcn_mfma_f32_16x16x32_bf16(af1, bf, acc, 0, 0, 0);
            }
            // D1: col n = 16nt + l15, rows o = 16w + 4*l4 + j  ->  yt[o][m=n]
            #pragma unroll
            for (int j = 0; j < 4; ++j) {
                int oo = 16*w + 4*l4 + j;
                int m  = n;
                int po = (m >> 3) ^ (oo & 7);
                *(short*)(smem + 16384 + oo*256 + po*16 + (m & 7)*2) = f2bf(acc[j] + bia[j]);
            }
        }
    }
    __syncthreads();

    // ---------------- per-relation loop ----------------
    f32x4 tot[4] = {{0,0,0,0},{0,0,0,0},{0,0,0,0},{0,0,0,0}};

    #pragma unroll 1
    for (int r = 0; r < 2; ++r) {
        const size_t aoff = ((size_t)(b*2 + r)*128 + t) * 16384;
        const float* gA = Ag + aoff;
        float*       gO = outg + XOUT_ELEMS + aoff;   // fused exact A-copy

        // ---- P2: stage A -> shAT (bf16 transposed, swizzled) + copy + fp32 rowsums ----
        // wave w owns rows m in [16w,16w+16): m = 16w + 8k + 4g + i
        {
            float vv[2][4][4];
            #pragma unroll
            for (int k = 0; k < 2; ++k)
                #pragma unroll
                for (int i = 0; i < 4; ++i) {
                    int m = 16*w + 8*k + 4*g + i;
                    float4 v = *(const float4*)(gA + m*128 + 4*h);
                    *(float4*)(gO + m*128 + 4*h) = v;
                    vv[k][i][0] = v.x; vv[k][i][1] = v.y; vv[k][i][2] = v.z; vv[k][i][3] = v.w;
                }
            #pragma unroll
            for (int k = 0; k < 2; ++k)
                #pragma unroll
                for (int i = 0; i < 4; ++i) {
                    float s = vv[k][i][0] + vv[k][i][1] + vv[k][i][2] + vv[k][i][3];
                    s += __shfl_xor(s, 16); s += __shfl_xor(s, 8);
                    s += __shfl_xor(s, 4);  s += __shfl_xor(s, 2); s += __shfl_xor(s, 1);
                    if (h == 0) rs[16*w + 8*k + 4*g + i] = s;   // rowsum over n of A[m][:]
                }
            #pragma unroll
            for (int k = 0; k < 2; ++k) {
                int po = (2*w + k) ^ (h & 7);        // m-oct = (16w+8k+4g)>>3 = 2w+k
                #pragma unroll
                for (int e = 0; e < 4; ++e) {
                    int n = 4*h + e;
                    short4v pk;
                    pk[0] = f2bf(vv[k][0][e]); pk[1] = f2bf(vv[k][1][e]);
                    pk[2] = f2bf(vv[k][2][e]); pk[3] = f2bf(vv[k][3][e]);
                    *(short4v*)(smem + 49152 + n*256 + po*16 + 8*g) = pk;
                }
            }
        }
        __syncthreads();

        // ---- P3: diagonal += 1 (A~ = A + I), and scale yt rows of this relation by d[m] ----
        if (tid < 128) {
            int n  = tid;
            int po = (n >> 3) ^ ((n >> 2) & 7);
            short* p = (short*)(smem + 49152 + n*256 + po*16 + (n & 7)*2);
            *p = f2bf(bf2f(*p) + 1.0f);
        }
        #pragma unroll
        for (int z = 0; z < 2; ++z) {
            int tau = tid + 512*z;                  // 1024 octet tasks: 64 rows x 16 phys octets
            int o   = 64*r + (tau >> 4);
            int po  = tau & 15;
            int oct = po ^ (o & 7);                 // logical m-octet
            short* yp = (short*)(smem + 16384 + o*256 + po*16);
            bf16x8 yv = *(bf16x8*)yp;
            int m0 = oct*8;
            f32x4 r0 = *(f32x4*)(rs + m0);
            f32x4 r1 = *(f32x4*)(rs + m0 + 4);
            float dv[8];
            dv[0] = rsqrtf(1.f + r0[0]); dv[1] = rsqrtf(1.f + r0[1]);
            dv[2] = rsqrtf(1.f + r0[2]); dv[3] = rsqrtf(1.f + r0[3]);
            dv[4] = rsqrtf(1.f + r1[0]); dv[5] = rsqrtf(1.f + r1[1]);
            dv[6] = rsqrtf(1.f + r1[2]); dv[7] = rsqrtf(1.f + r1[3]);
            bf16x8 yo;
            #pragma unroll
            for (int e = 0; e < 8; ++e) yo[e] = f2bf(bf2f(yv[e]) * dv[e]);
            *(bf16x8*)yp = yo;
        }
        __syncthreads();

        // ---- P4: GEMM2  D[c][n] = sum_m yd[64r+c][m] * A~[m][n], tot += d[n]*D ----
        // wave w -> n-block [16w,16w+16); c-tiles 0..3; k = m, 4 ksteps.
        {
            f32x4 acc[4] = {{0,0,0,0},{0,0,0,0},{0,0,0,0},{0,0,0,0}};
            const int n    = 16*w + l15;
            const int keyA = (n >> 2) & 7;
            #pragma unroll
            for (int s = 0; s < 4; ++s) {
                int octk = 4*s + l4;
                bf16x8 bfr = *(const bf16x8*)(smem + 49152 + n*256 + (octk ^ keyA)*16);
                #pragma unroll
                for (int ct = 0; ct < 4; ++ct) {
                    int o  = 64*r + 16*ct + l15;
                    bf16x8 afr = *(const bf16x8*)(smem + 16384 + o*256 + (octk ^ (o & 7))*16);
                    acc[ct] = __builtin_amdgcn_mfma_f32_16x16x32_bf16(afr, bfr, acc[ct], 0, 0, 0);
                }
            }
            float dn = rsqrtf(1.f + rs[n]);
            #pragma unroll
            for (int ct = 0; ct < 4; ++ct)
                #pragma unroll
                for (int j = 0; j < 4; ++j) tot[ct][j] += acc[ct][j] * dn;
        }
        __syncthreads();   // before next r overwrites shAT/rs
    }

    // ---------------- epilogue: x_out[b, c, t, n] ----------------
    // lane holds col n = 16w + l15, rows c = 16ct + 4*l4 + j -> 4x64B segments per store instr
    #pragma unroll
    for (int ct = 0; ct < 4; ++ct)
        #pragma unroll
        for (int j = 0; j < 4; ++j) {
            int c = 16*ct + 4*l4 + j;
            int n = 16*w + l15;
            outg[((size_t)(b*64 + c)*128 + t)*128 + n] = tot[ct][j];
        }
}

extern "C" void kernel_launch(void* const* d_in, const int* in_sizes, int n_in,
                              void* d_out, int out_size, void* d_ws, size_t ws_size,
                              hipStream_t stream) {
    const float* x    = (const float*)d_in[0];
    const float* A    = (const float*)d_in[1];
    const float* W    = (const float*)d_in[2];
    const float* bias = (const float*)d_in[3];
    float* out = (float*)d_out;

    dim3 grid(32 * 128);   // one block per (b, t)
    dim3 block(TB);
    hipLaunchKernelGGL(gcn_fused, grid, block, 0, stream, x, A, W, bias, out);
}

// Round 3
// 252.225 us; speedup vs baseline: 2.5279x; 1.0100x over previous
//
#include <hip/hip_runtime.h>
#include <hip/hip_bf16.h>

#define TB 512

// B=32, R=2, T=128, N=128, C_IN=64, C_OUT=64
constexpr size_t XOUT_ELEMS = 32ull * 64 * 128 * 128;  // 33,554,432

typedef short bf16x8  __attribute__((ext_vector_type(8)));
typedef short short4v __attribute__((ext_vector_type(4)));
typedef float f32x4   __attribute__((ext_vector_type(4)));

static __device__ __forceinline__ short f2bf(float f) {
    __hip_bfloat16 hb = __float2bfloat16(f);           // RNE
    return *reinterpret_cast<short*>(&hb);
}

// LDS byte map (81920 B total = 2 blocks/CU of the 160 KiB pool):
//  [0,16384)      shXT: x^T bf16, row n stride 128B; elem (n,c): n*128 + po*16 + (c&7)*2,
//                 po = (c>>3) ^ ((n>>2)&7).   Dead after GEMM1; [0,512) reused as dd[128] f32.
//  [16384,49152)  yt: y[o][m] bf16 (read-only after P1), row o stride 256B;
//                 elem: 16384 + o*256 + po*16 + (m&7)*2, po = (m>>3) ^ (o&7)
//  [49152,81920)  shAT: holds d[m]*(A+I)[m][n] bf16, transposed (row n, col m);
//                 elem: 49152 + n*256 + po*16 + (m&7)*2, po = (m>>3) ^ ((n>>2)&7)

__global__ __launch_bounds__(TB, 4)
void gcn_fused(const float* __restrict__ xg, const float* __restrict__ Ag,
               const float* __restrict__ Wg, const float* __restrict__ bg,
               float* __restrict__ outg)
{
    __shared__ float4 smem4[5120];
    char*  smem = (char*)smem4;
    float* dd   = (float*)smem;   // d[m] = rsqrt(1 + rowsum(A[m,:])), per relation

    const int tid = threadIdx.x;
    const int w   = tid >> 6;     // wave 0..7
    const int l   = tid & 63;
    const int g   = l >> 5;       // half-wave
    const int h   = l & 31;
    const int l15 = l & 15;
    const int l4  = l >> 4;       // 0..3

    const int blk = blockIdx.x;
    const int b = blk >> 7, t = blk & 127;

    // ---------------- P0: stage x^T (bf16, swizzled) ----------------
    {
        float vv[4][4];
        #pragma unroll
        for (int i = 0; i < 4; ++i) {
            int c = 8*w + 4*g + i;
            float4 v = *(const float4*)(xg + ((size_t)(b*64 + c)*128 + t)*128 + 4*h);
            vv[i][0] = v.x; vv[i][1] = v.y; vv[i][2] = v.z; vv[i][3] = v.w;
        }
        int po = w ^ (h & 7);                       // c-oct = w ; key = (n>>2)&7 = h&7
        #pragma unroll
        for (int e = 0; e < 4; ++e) {
            int n = 4*h + e;
            short4v pk;
            pk[0] = f2bf(vv[0][e]); pk[1] = f2bf(vv[1][e]);
            pk[2] = f2bf(vv[2][e]); pk[3] = f2bf(vv[3][e]);
            *(short4v*)(smem + n*128 + po*16 + 8*g) = pk;
        }
    }
    __syncthreads();

    // ---------------- P1: GEMM1  y[o][n] = W[o][:]·x[:][n] + b[o]  (MFMA) ----------------
    {
        bf16x8 af0, af1;
        float  bia[4];
        const int o = 16*w + l15;
        const float* wp0 = Wg + o*64 + 8*l4;
        const float* wp1 = wp0 + 32;
        #pragma unroll
        for (int e = 0; e < 8; ++e) { af0[e] = f2bf(wp0[e]); af1[e] = f2bf(wp1[e]); }
        #pragma unroll
        for (int j = 0; j < 4; ++j) bia[j] = bg[16*w + 4*l4 + j];

        #pragma unroll
        for (int nt = 0; nt < 8; ++nt) {
            f32x4 acc = {0.f, 0.f, 0.f, 0.f};
            int n   = 16*nt + l15;
            int key = (n >> 2) & 7;
            {
                int po = l4 ^ key;
                bf16x8 bf = *(const bf16x8*)(smem + n*128 + po*16);
                acc = __builtin_amdgcn_mfma_f32_16x16x32_bf16(af0, bf, acc, 0, 0, 0);
            }
            {
                int po = (4 + l4) ^ key;
                bf16x8 bf = *(const bf16x8*)(smem + n*128 + po*16);
                acc = __builtin_amdgcn_mfma_f32_16x16x32_bf16(af1, bf, acc, 0, 0, 0);
            }
            #pragma unroll
            for (int j = 0; j < 4; ++j) {
                int oo = 16*w + 4*l4 + j;
                int m  = n;
                int po = (m >> 3) ^ (oo & 7);
                *(short*)(smem + 16384 + oo*256 + po*16 + (m & 7)*2) = f2bf(acc[j] + bia[j]);
            }
        }
    }
    __syncthreads();

    // ---------------- per-relation loop ----------------
    f32x4 tot[4] = {{0,0,0,0},{0,0,0,0},{0,0,0,0},{0,0,0,0}};

    #pragma unroll 1
    for (int r = 0; r < 2; ++r) {
        const size_t aoff = ((size_t)(b*2 + r)*128 + t) * 16384;
        const float* gA = Ag + aoff;
        float*       gO = outg + XOUT_ELEMS + aoff;   // fused exact A-copy

        // ---- P2: stage d[m]*(A+I) -> shAT (bf16 transposed, swizzled)
        //          + exact copy + in-register rowsum/normalization ----
        // wave w owns rows m in [16w,16w+16): m = 16w + 8k + 4g + i
        {
            float vv[2][4][4];
            #pragma unroll
            for (int k = 0; k < 2; ++k)
                #pragma unroll
                for (int i = 0; i < 4; ++i) {
                    int m = 16*w + 8*k + 4*g + i;
                    float4 v = *(const float4*)(gA + m*128 + 4*h);
                    *(float4*)(gO + m*128 + 4*h) = v;   // raw copy before any edit
                    vv[k][i][0] = v.x; vv[k][i][1] = v.y;
                    vv[k][i][2] = v.z; vv[k][i][3] = v.w;
                }
            #pragma unroll
            for (int k = 0; k < 2; ++k)
                #pragma unroll
                for (int i = 0; i < 4; ++i) {
                    float s = vv[k][i][0] + vv[k][i][1] + vv[k][i][2] + vv[k][i][3];
                    s += __shfl_xor(s, 16); s += __shfl_xor(s, 8);
                    s += __shfl_xor(s, 4);  s += __shfl_xor(s, 2); s += __shfl_xor(s, 1);
                    float dv = rsqrtf(1.0f + s);        // all 32 lanes hold rowsum
                    if (h == 4*w + 2*k + g) vv[k][i][i] += 1.0f;   // += I at col m
                    vv[k][i][0] *= dv; vv[k][i][1] *= dv;
                    vv[k][i][2] *= dv; vv[k][i][3] *= dv;
                    if (h == 0) dd[16*w + 8*k + 4*g + i] = dv;
                }
            #pragma unroll
            for (int k = 0; k < 2; ++k) {
                int po = (2*w + k) ^ (h & 7);           // m-oct = 2w+k
                #pragma unroll
                for (int e = 0; e < 4; ++e) {
                    int n = 4*h + e;
                    short4v pk;
                    pk[0] = f2bf(vv[k][0][e]); pk[1] = f2bf(vv[k][1][e]);
                    pk[2] = f2bf(vv[k][2][e]); pk[3] = f2bf(vv[k][3][e]);
                    *(short4v*)(smem + 49152 + n*256 + po*16 + 8*g) = pk;
                }
            }
        }
        __syncthreads();

        // ---- P4: GEMM2  D[c][n] = sum_m y[64r+c][m] * (d[m]A~[m][n]), tot += d[n]*D ----
        {
            f32x4 acc[4] = {{0,0,0,0},{0,0,0,0},{0,0,0,0},{0,0,0,0}};
            const int n    = 16*w + l15;
            const int keyA = (n >> 2) & 7;
            #pragma unroll
            for (int s = 0; s < 4; ++s) {
                int octk = 4*s + l4;
                bf16x8 bfr = *(const bf16x8*)(smem + 49152 + n*256 + (octk ^ keyA)*16);
                #pragma unroll
                for (int ct = 0; ct < 4; ++ct) {
                    int o  = 64*r + 16*ct + l15;
                    bf16x8 afr = *(const bf16x8*)(smem + 16384 + o*256 + (octk ^ (o & 7))*16);
                    acc[ct] = __builtin_amdgcn_mfma_f32_16x16x32_bf16(afr, bfr, acc[ct], 0, 0, 0);
                }
            }
            float dn = dd[n];
            #pragma unroll
            for (int ct = 0; ct < 4; ++ct)
                #pragma unroll
                for (int j = 0; j < 4; ++j) tot[ct][j] += acc[ct][j] * dn;
        }
        __syncthreads();   // before next r overwrites shAT/dd
    }

    // ---------------- epilogue: x_out[b, c, t, n] ----------------
    #pragma unroll
    for (int ct = 0; ct < 4; ++ct)
        #pragma unroll
        for (int j = 0; j < 4; ++j) {
            int c = 16*ct + 4*l4 + j;
            int n = 16*w + l15;
            outg[((size_t)(b*64 + c)*128 + t)*128 + n] = tot[ct][j];
        }
}

extern "C" void kernel_launch(void* const* d_in, const int* in_sizes, int n_in,
                              void* d_out, int out_size, void* d_ws, size_t ws_size,
                              hipStream_t stream) {
    const float* x    = (const float*)d_in[0];
    const float* A    = (const float*)d_in[1];
    const float* W    = (const float*)d_in[2];
    const float* bias = (const float*)d_in[3];
    float* out = (float*)d_out;

    dim3 grid(32 * 128);   // one block per (b, t)
    dim3 block(TB);
    hipLaunchKernelGGL(gcn_fused, grid, block, 0, stream, x, A, W, bias, out);
}

// Round 5
// 236.379 us; speedup vs baseline: 2.6974x; 1.0670x over previous
//
#include <hip/hip_runtime.h>
#include <hip/hip_bf16.h>

#define TB 512

// B=32, R=2, T=128, N=128, C_IN=64, C_OUT=64
constexpr size_t XOUT_ELEMS = 32ull * 64 * 128 * 128;  // 33,554,432

typedef short bf16x8  __attribute__((ext_vector_type(8)));
typedef short short4v __attribute__((ext_vector_type(4)));
typedef float f32x4   __attribute__((ext_vector_type(4)));

static __device__ __forceinline__ short f2bf(float f) {
    __hip_bfloat16 hb = __float2bfloat16(f);           // RNE
    return *reinterpret_cast<short*>(&hb);
}

// LDS byte map (81920 B = 2 blocks/CU of the 160 KiB pool):
//  [0,16384)      shXT: x^T bf16, row n stride 128B; elem (n,c): n*128 + po*16 + (c&7)*2,
//                 po = (c>>3) ^ ((n>>2)&7).   Dead after P1; [0,512) reused as dd[128] f32.
//  [16384,49152)  yt: y[o][m] bf16 (read-only after P1), row o stride 256B;
//                 elem: 16384 + o*256 + po*16 + (m&7)*2, po = (m>>3) ^ (o&7)
//  [49152,81920)  P0/P1: shW bf16 [o][c], row o stride 128B; elem: o*128 + po*16 + (c&7)*2,
//                 po = (c>>3) ^ (o&7).
//                 Relation loop: shAT = d[m]*(A+I)[m][n] bf16 transposed (row n, col m);
//                 elem: 49152 + n*256 + po*16 + (m&7)*2, po = (m>>3) ^ ((n>>2)&7)

__global__ __launch_bounds__(TB, 4)
void gcn_fused(const float* __restrict__ xg, const float* __restrict__ Ag,
               const float* __restrict__ Wg, const float* __restrict__ bg,
               float* __restrict__ outg)
{
    __shared__ float4 smem4[5120];
    char*  smem = (char*)smem4;
    float* dd   = (float*)smem;   // d[m] per relation

    const int tid = threadIdx.x;
    const int w   = tid >> 6;     // wave 0..7
    const int l   = tid & 63;
    const int g   = l >> 5;
    const int h   = l & 31;
    const int l15 = l & 15;
    const int l4  = l >> 4;       // 0..3

    const int blk = blockIdx.x;
    const int b = blk >> 7, t = blk & 127;

    // ---------------- P0a: stage x^T (bf16, swizzled), NT loads ----------------
    {
        float vv[4][4];
        #pragma unroll
        for (int i = 0; i < 4; ++i) {
            int c = 8*w + 4*g + i;
            f32x4 v = __builtin_nontemporal_load(
                (const f32x4*)(xg + ((size_t)(b*64 + c)*128 + t)*128 + 4*h));
            vv[i][0] = v[0]; vv[i][1] = v[1]; vv[i][2] = v[2]; vv[i][3] = v[3];
        }
        int po = w ^ (h & 7);                       // c-oct = w ; key = (n>>2)&7 = h&7
        #pragma unroll
        for (int e = 0; e < 4; ++e) {
            int n = 4*h + e;
            short4v pk;
            pk[0] = f2bf(vv[0][e]); pk[1] = f2bf(vv[1][e]);
            pk[2] = f2bf(vv[2][e]); pk[3] = f2bf(vv[3][e]);
            *(short4v*)(smem + n*128 + po*16 + 8*g) = pk;
        }
    }
    // ---------------- P0b: stage W -> shW bf16 (coalesced, cached loads) ----------------
    #pragma unroll
    for (int k2 = 0; k2 < 4; ++k2) {
        int q = tid + TB*k2;                        // < 2048 float4 chunks of W
        f32x4 v = ((const f32x4*)Wg)[q];
        int o = q >> 4, oct = (q >> 1) & 7, hf = q & 1;
        short4v pk;
        pk[0] = f2bf(v[0]); pk[1] = f2bf(v[1]); pk[2] = f2bf(v[2]); pk[3] = f2bf(v[3]);
        *(short4v*)(smem + 49152 + o*128 + (oct ^ (o & 7))*16 + hf*8) = pk;
    }
    // ---------------- P0c: bias per D-column (o = 16*ot + l15) ----------------
    float bia[8];
    #pragma unroll
    for (int ot = 0; ot < 8; ++ot) bia[ot] = bg[16*ot + l15];
    __syncthreads();

    // ---------------- P1: GEMM1, swapped operands: D[n][o] = xT·W^T ----------------
    // A-op = xT rows n (loop-invariant!), B-op = W rows o. Lane holds col o = 16ot+l15,
    // rows n = 16w + 4*l4 + j -> 4 consecutive m at fixed o -> packed b64 yt writes.
    {
        const int n    = 16*w + l15;
        const int keyx = (n >> 2) & 7;
        bf16x8 af0 = *(const bf16x8*)(smem + n*128 + ((0 + l4) ^ keyx)*16);
        bf16x8 af1 = *(const bf16x8*)(smem + n*128 + ((4 + l4) ^ keyx)*16);
        const int m0   = 16*w + 4*l4;               // D row base (m = n-axis of yt)
        const int pob  = m0 >> 3;                   // = 2w + (l4>>1)
        const int keyw = l15 & 7;                   // o & 7
        #pragma unroll
        for (int ot = 0; ot < 8; ++ot) {
            int o = 16*ot + l15;
            f32x4 acc = {0.f, 0.f, 0.f, 0.f};
            bf16x8 bf0 = *(const bf16x8*)(smem + 49152 + o*128 + ((0 + l4) ^ keyw)*16);
            bf16x8 bf1 = *(const bf16x8*)(smem + 49152 + o*128 + ((4 + l4) ^ keyw)*16);
            acc = __builtin_amdgcn_mfma_f32_16x16x32_bf16(af0, bf0, acc, 0, 0, 0);
            acc = __builtin_amdgcn_mfma_f32_16x16x32_bf16(af1, bf1, acc, 0, 0, 0);
            short4v pk;
            pk[0] = f2bf(acc[0] + bia[ot]); pk[1] = f2bf(acc[1] + bia[ot]);
            pk[2] = f2bf(acc[2] + bia[ot]); pk[3] = f2bf(acc[3] + bia[ot]);
            int po = pob ^ (o & 7);
            *(short4v*)(smem + 16384 + o*256 + po*16 + (m0 & 7)*2) = pk;
        }
    }
    __syncthreads();

    // ---------------- per-relation loop ----------------
    f32x4 tot[4] = {{0,0,0,0},{0,0,0,0},{0,0,0,0},{0,0,0,0}};

    #pragma unroll 1
    for (int r = 0; r < 2; ++r) {
        const size_t aoff = ((size_t)(b*2 + r)*128 + t) * 16384;
        const float* gA = Ag + aoff;
        float*       gO = outg + XOUT_ELEMS + aoff;   // fused exact A-copy

        // ---- P2: stage d[m]*(A+I) -> shAT + exact NT copy + in-register rowsums ----
        {
            float vv[2][4][4];
            #pragma unroll
            for (int k = 0; k < 2; ++k)
                #pragma unroll
                for (int i = 0; i < 4; ++i) {
                    int m = 16*w + 8*k + 4*g + i;
                    f32x4 v = __builtin_nontemporal_load((const f32x4*)(gA + m*128 + 4*h));
                    __builtin_nontemporal_store(v, (f32x4*)(gO + m*128 + 4*h));
                    vv[k][i][0] = v[0]; vv[k][i][1] = v[1];
                    vv[k][i][2] = v[2]; vv[k][i][3] = v[3];
                }
            #pragma unroll
            for (int k = 0; k < 2; ++k)
                #pragma unroll
                for (int i = 0; i < 4; ++i) {
                    float s = vv[k][i][0] + vv[k][i][1] + vv[k][i][2] + vv[k][i][3];
                    s += __shfl_xor(s, 16); s += __shfl_xor(s, 8);
                    s += __shfl_xor(s, 4);  s += __shfl_xor(s, 2); s += __shfl_xor(s, 1);
                    float dv = rsqrtf(1.0f + s);
                    if (h == 4*w + 2*k + g) vv[k][i][i] += 1.0f;   // += I at col m
                    vv[k][i][0] *= dv; vv[k][i][1] *= dv;
                    vv[k][i][2] *= dv; vv[k][i][3] *= dv;
                    if (h == 0) dd[16*w + 8*k + 4*g + i] = dv;
                }
            #pragma unroll
            for (int k = 0; k < 2; ++k) {
                int po = (2*w + k) ^ (h & 7);           // m-oct = 2w+k
                #pragma unroll
                for (int e = 0; e < 4; ++e) {
                    int n = 4*h + e;
                    short4v pk;
                    pk[0] = f2bf(vv[k][0][e]); pk[1] = f2bf(vv[k][1][e]);
                    pk[2] = f2bf(vv[k][2][e]); pk[3] = f2bf(vv[k][3][e]);
                    *(short4v*)(smem + 49152 + n*256 + po*16 + 8*g) = pk;
                }
            }
        }
        __syncthreads();

        // ---- P4: GEMM2  D[c][n] = sum_m y[64r+c][m] * (d[m]A~[m][n]), tot += d[n]*D ----
        {
            f32x4 acc[4] = {{0,0,0,0},{0,0,0,0},{0,0,0,0},{0,0,0,0}};
            const int n    = 16*w + l15;
            const int keyA = (n >> 2) & 7;
            #pragma unroll
            for (int s = 0; s < 4; ++s) {
                int octk = 4*s + l4;
                bf16x8 bfr = *(const bf16x8*)(smem + 49152 + n*256 + (octk ^ keyA)*16);
                #pragma unroll
                for (int ct = 0; ct < 4; ++ct) {
                    int o  = 64*r + 16*ct + l15;
                    bf16x8 afr = *(const bf16x8*)(smem + 16384 + o*256 + (octk ^ (o & 7))*16);
                    acc[ct] = __builtin_amdgcn_mfma_f32_16x16x32_bf16(afr, bfr, acc[ct], 0, 0, 0);
                }
            }
            float dn = dd[n];
            #pragma unroll
            for (int ct = 0; ct < 4; ++ct)
                #pragma unroll
                for (int j = 0; j < 4; ++j) tot[ct][j] += acc[ct][j] * dn;
        }
        __syncthreads();   // before next r overwrites shAT/dd
    }

    // ---------------- epilogue: x_out[b, c, t, n], NT stores ----------------
    #pragma unroll
    for (int ct = 0; ct < 4; ++ct)
        #pragma unroll
        for (int j = 0; j < 4; ++j) {
            int c = 16*ct + 4*l4 + j;
            int n = 16*w + l15;
            __builtin_nontemporal_store(tot[ct][j],
                &outg[((size_t)(b*64 + c)*128 + t)*128 + n]);
        }
}

extern "C" void kernel_launch(void* const* d_in, const int* in_sizes, int n_in,
                              void* d_out, int out_size, void* d_ws, size_t ws_size,
                              hipStream_t stream) {
    const float* x    = (const float*)d_in[0];
    const float* A    = (const float*)d_in[1];
    const float* W    = (const float*)d_in[2];
    const float* bias = (const float*)d_in[3];
    float* out = (float*)d_out;

    dim3 grid(32 * 128);   // one block per (b, t)
    dim3 block(TB);
    hipLaunchKernelGGL(gcn_fused, grid, block, 0, stream, x, A, W, bias, out);
}